// Round 2
// baseline (49.959 us; speedup 1.0000x reference)
//
#include <hip/hip_runtime.h>

typedef float f4 __attribute__((ext_vector_type(4)));

constexpr int MAXL = 3;
constexpr int NANG = 20;   // angular basis size for MAX_L=3
constexpr int N2   = 19;   // quadratic table rows
constexpr int N3   = 108;  // cubic table rows
constexpr int NG2  = 3;
constexpr int NG3  = 4;
constexpr int NOUT = 1 + NG2 + NG3; // 8
constexpr int NCH  = 32;

constexpr int fact(int n) { return n <= 1 ? 1 : n * fact(n - 1); }

// replicate Python _l_list(3) enumeration -> index of (lx,ly,lz)
constexpr int lidx_of(int lx, int ly, int lz) {
    int idx = 0;
    for (int L = 0; L <= MAXL; ++L)
        for (int ax = L; ax >= 0; --ax)
            for (int ay = L - ax; ay >= 0; --ay) {
                if (ax == lx && ay == ly && (L - ax - ay) == lz) return idx;
                ++idx;
            }
    return -1;
}
constexpr float mnom(int a, int b, int c) {
    return (float)(fact(a + b + c) / (fact(a) * fact(b) * fact(c)));
}

// compile-time replica of _build_tables(3)
struct Tab {
    int   i2a[N2] {}, i2b[N2] {}; float p2[N2] {}; int s2[N2] {};
    int   i3a[N3] {}, i3b[N3] {}, i3c[N3] {}; float p3[N3] {}; int s3[N3] {};
    constexpr Tab() {
        int n = 0;
        for (int L = 1; L <= MAXL; ++L)
            for (int a = 0; a <= L; ++a)
                for (int b = 0; b <= L - a; ++b) {
                    int c = L - a - b;
                    i2a[n] = lidx_of(a, b, c); i2b[n] = i2a[n];
                    p2[n] = mnom(a, b, c); s2[n] = L - 1; ++n;
                }
        int g = 0, m = 0;
        for (int A = 1; A <= MAXL; ++A)
            for (int B = 0; B <= A; ++B)
                for (int C = 0; C <= B; ++C) {
                    if (!(B + C >= 1 && A + B <= MAXL && B + C <= MAXL)) continue;
                    for (int a12 = 0; a12 <= A; ++a12)
                        for (int b12 = 0; b12 <= A - a12; ++b12) {
                            int c12 = A - a12 - b12;
                            for (int a13 = 0; a13 <= B; ++a13)
                                for (int b13 = 0; b13 <= B - a13; ++b13) {
                                    int c13 = B - a13 - b13;
                                    for (int a23 = 0; a23 <= C; ++a23)
                                        for (int b23 = 0; b23 <= C - a23; ++b23) {
                                            int c23 = C - a23 - b23;
                                            i3a[m] = lidx_of(a12 + a13, b12 + b13, c12 + c13);
                                            i3b[m] = lidx_of(a12 + a23, b12 + b23, c12 + c23);
                                            i3c[m] = lidx_of(a13 + a23, b13 + b23, c13 + c23);
                                            p3[m]  = mnom(a12, b12, c12) * mnom(a13, b13, c13)
                                                   * mnom(a23, b23, c23);
                                            s3[m]  = g; ++m;
                                        }
                                }
                        }
                    ++g;
                }
    }
};
constexpr Tab TAB {};

__global__ __launch_bounds__(256) void symm_kernel(
    const float* __restrict__ in, float* __restrict__ out, int total)
{
    int t = blockIdx.x * 256 + threadIdx.x;
    if (t >= total) return;
    int c4 = t & 7;   // which float4 of the 32 channels
    int rn = t >> 3;  // node*radial row

    const float* ip = in + (size_t)rn * (NANG * NCH) + c4 * 4;
    f4 x[NANG];
    #pragma unroll
    for (int a = 0; a < NANG; ++a)
        x[a] = __builtin_nontemporal_load(reinterpret_cast<const f4*>(ip + a * NCH));

    f4 acc[NOUT];
    acc[0] = x[0];
    #pragma unroll
    for (int i = 1; i < NOUT; ++i) acc[i] = 0.f;

    // quadratic: acc[1 + seg] += p * x[i]*x[j]  (indices fold to immediates)
    #pragma unroll
    for (int k = 0; k < N2; ++k)
        acc[1 + TAB.s2[k]] += (TAB.p2[k] * x[TAB.i2a[k]]) * x[TAB.i2b[k]];

    // cubic: acc[1 + NG2 + grp] += p * x[i]*x[j]*x[k]
    #pragma unroll
    for (int k = 0; k < N3; ++k)
        acc[1 + NG2 + TAB.s3[k]] +=
            ((TAB.p3[k] * x[TAB.i3a[k]]) * x[TAB.i3b[k]]) * x[TAB.i3c[k]];

    float* op = out + (size_t)rn * (NOUT * NCH) + c4 * 4;
    #pragma unroll
    for (int o = 0; o < NOUT; ++o)
        __builtin_nontemporal_store(acc[o], reinterpret_cast<f4*>(op + o * NCH));
}

extern "C" void kernel_launch(void* const* d_in, const int* in_sizes, int n_in,
                              void* d_out, int out_size, void* d_ws, size_t ws_size,
                              hipStream_t stream) {
    const float* in = (const float*)d_in[0];
    float* out = (float*)d_out;
    // in_sizes[0] = n_nodes * N_RADIAL * NANG * NCH
    int rn_total = in_sizes[0] / (NANG * NCH);   // n_nodes * N_RADIAL
    int total    = rn_total * (NCH / 4);         // threads (one per float4)
    int blocks   = (total + 255) / 256;
    symm_kernel<<<blocks, 256, 0, stream>>>(in, out, total);
}

// Round 3
// 48.704 us; speedup vs baseline: 1.0258x; 1.0258x over previous
//
#include <hip/hip_runtime.h>

typedef float f4 __attribute__((ext_vector_type(4)));

constexpr int MAXL = 3;
constexpr int NANG = 20;   // angular basis size for MAX_L=3
constexpr int N2   = 19;   // quadratic table rows
constexpr int N3   = 108;  // cubic table rows
constexpr int NG2  = 3;
constexpr int NG3  = 4;
constexpr int NOUT = 1 + NG2 + NG3; // 8
constexpr int NCH  = 32;

constexpr int fact(int n) { return n <= 1 ? 1 : n * fact(n - 1); }

// replicate Python _l_list(3) enumeration -> index of (lx,ly,lz)
constexpr int lidx_of(int lx, int ly, int lz) {
    int idx = 0;
    for (int L = 0; L <= MAXL; ++L)
        for (int ax = L; ax >= 0; --ax)
            for (int ay = L - ax; ay >= 0; --ay) {
                if (ax == lx && ay == ly && (L - ax - ay) == lz) return idx;
                ++idx;
            }
    return -1;
}
constexpr float mnom(int a, int b, int c) {
    return (float)(fact(a + b + c) / (fact(a) * fact(b) * fact(c)));
}

// compile-time replica of _build_tables(3)
struct Tab {
    int   i2a[N2] {}, i2b[N2] {}; float p2[N2] {}; int s2[N2] {};
    int   i3a[N3] {}, i3b[N3] {}, i3c[N3] {}; float p3[N3] {}; int s3[N3] {};
    constexpr Tab() {
        int n = 0;
        for (int L = 1; L <= MAXL; ++L)
            for (int a = 0; a <= L; ++a)
                for (int b = 0; b <= L - a; ++b) {
                    int c = L - a - b;
                    i2a[n] = lidx_of(a, b, c); i2b[n] = i2a[n];
                    p2[n] = mnom(a, b, c); s2[n] = L - 1; ++n;
                }
        int g = 0, m = 0;
        for (int A = 1; A <= MAXL; ++A)
            for (int B = 0; B <= A; ++B)
                for (int C = 0; C <= B; ++C) {
                    if (!(B + C >= 1 && A + B <= MAXL && B + C <= MAXL)) continue;
                    for (int a12 = 0; a12 <= A; ++a12)
                        for (int b12 = 0; b12 <= A - a12; ++b12) {
                            int c12 = A - a12 - b12;
                            for (int a13 = 0; a13 <= B; ++a13)
                                for (int b13 = 0; b13 <= B - a13; ++b13) {
                                    int c13 = B - a13 - b13;
                                    for (int a23 = 0; a23 <= C; ++a23)
                                        for (int b23 = 0; b23 <= C - a23; ++b23) {
                                            int c23 = C - a23 - b23;
                                            i3a[m] = lidx_of(a12 + a13, b12 + b13, c12 + c13);
                                            i3b[m] = lidx_of(a12 + a23, b12 + b23, c12 + c23);
                                            i3c[m] = lidx_of(a13 + a23, b13 + b23, c13 + c23);
                                            p3[m]  = mnom(a12, b12, c12) * mnom(a13, b13, c13)
                                                   * mnom(a23, b23, c23);
                                            s3[m]  = g; ++m;
                                        }
                                }
                        }
                    ++g;
                }
    }
};
constexpr Tab TAB {};

__global__ __launch_bounds__(256) void symm_kernel(
    const float* __restrict__ in, float* __restrict__ out, int total)
{
    int t = blockIdx.x * 256 + threadIdx.x;
    if (t >= total) return;
    int c4 = t & 7;   // which float4 of the 32 channels
    int rn = t >> 3;  // node*radial row

    const float* ip = in + (size_t)rn * (NANG * NCH) + c4 * 4;
    f4 x[NANG];
    #pragma unroll
    for (int a = 0; a < NANG; ++a)
        x[a] = *reinterpret_cast<const f4*>(ip + a * NCH);

    f4 acc[NOUT];
    acc[0] = x[0];
    #pragma unroll
    for (int i = 1; i < NOUT; ++i) acc[i] = 0.f;

    // quadratic: acc[1 + seg] += p * x[i]*x[j]  (indices fold to immediates)
    #pragma unroll
    for (int k = 0; k < N2; ++k)
        acc[1 + TAB.s2[k]] += (TAB.p2[k] * x[TAB.i2a[k]]) * x[TAB.i2b[k]];

    // cubic: acc[1 + NG2 + grp] += p * x[i]*x[j]*x[k]
    #pragma unroll
    for (int k = 0; k < N3; ++k)
        acc[1 + NG2 + TAB.s3[k]] +=
            ((TAB.p3[k] * x[TAB.i3a[k]]) * x[TAB.i3b[k]]) * x[TAB.i3c[k]];

    float* op = out + (size_t)rn * (NOUT * NCH) + c4 * 4;
    #pragma unroll
    for (int o = 0; o < NOUT; ++o)
        *reinterpret_cast<f4*>(op + o * NCH) = acc[o];
}

extern "C" void kernel_launch(void* const* d_in, const int* in_sizes, int n_in,
                              void* d_out, int out_size, void* d_ws, size_t ws_size,
                              hipStream_t stream) {
    const float* in = (const float*)d_in[0];
    float* out = (float*)d_out;
    // in_sizes[0] = n_nodes * N_RADIAL * NANG * NCH
    int rn_total = in_sizes[0] / (NANG * NCH);   // n_nodes * N_RADIAL
    int total    = rn_total * (NCH / 4);         // threads (one per float4)
    int blocks   = (total + 255) / 256;
    symm_kernel<<<blocks, 256, 0, stream>>>(in, out, total);
}